// Round 1
// baseline (32.992 us; speedup 1.0000x reference)
//
#include <hip/hip_runtime.h>
#include <stdint.h>

// Problem constants (match reference)
constexpr int NB = 256;      // batch
constexpr int NS = 64;       // sequence
constexpr int NIB = 32;      // bits per token
constexpr int NH = 4;        // heads
constexpr int SIMB = 12;     // sim address bits
constexpr int VALB = 10;     // val address bits
constexpr int OUTB = 12;     // out address bits

// Packed table sizes (uint32 words)
constexpr int TOK_WORDS = NB * NS;        // 16384 : tokens[b,s] -> 32 bits
constexpr int SIM_WORDS = NH * 128;       // 512   : sim_mem[h] -> 4096 bits
constexpr int VAL_WORDS = NH * NIB * 32;  // 4096  : val_mem[h,n] -> 1024 bits
constexpr int AGG_WORDS = NH * NIB * 3;   // 384   : agg_mem[h,n] -> 65 bits (in 96)

__device__ __forceinline__ uint32_t pack32_f4(const float* __restrict__ p) {
    uint32_t v = 0;
    const float4* q = reinterpret_cast<const float4*>(p);
#pragma unroll
    for (int k = 0; k < 8; ++k) {
        float4 f = q[k];
        v |= (uint32_t)(f.x > 0.5f) << (4 * k + 0);
        v |= (uint32_t)(f.y > 0.5f) << (4 * k + 1);
        v |= (uint32_t)(f.z > 0.5f) << (4 * k + 2);
        v |= (uint32_t)(f.w > 0.5f) << (4 * k + 3);
    }
    return v;
}

__global__ __launch_bounds__(256) void pack_kernel(
    const int* __restrict__ tokens, const float* __restrict__ sim_mem,
    const float* __restrict__ val_mem, const float* __restrict__ agg_mem,
    uint32_t* __restrict__ ws)
{
    int tid = blockIdx.x * blockDim.x + threadIdx.x;
    uint32_t* wtok = ws;
    uint32_t* wsim = ws + TOK_WORDS;
    uint32_t* wval = wsim + SIM_WORDS;
    uint32_t* wagg = wval + VAL_WORDS;
    if (tid < TOK_WORDS) {
        const int* p = tokens + tid * NIB;
        uint32_t v = 0;
#pragma unroll
        for (int c = 0; c < NIB; ++c) v |= (uint32_t)(p[c] & 1) << c;
        wtok[tid] = v;
    }
    if (tid < SIM_WORDS) wsim[tid] = pack32_f4(sim_mem + tid * 32);
    if (tid < VAL_WORDS) wval[tid] = pack32_f4(val_mem + tid * 32);
    if (tid < AGG_WORDS) {
        int hn = tid / 3, w = tid % 3;
        uint32_t v = 0;
        for (int c = 0; c < 32; ++c) {
            int cnt = w * 32 + c;
            if (cnt < NS + 1) v |= (uint32_t)(agg_mem[hn * (NS + 1) + cnt] > 0.5f) << c;
        }
        wagg[tid] = v;
    }
}

// One block per batch b; 256 threads.
template <bool USE_WS>
__global__ __launch_bounds__(256) void ram_main(
    const uint32_t* __restrict__ ws,
    const int* __restrict__ tokens,
    const int* __restrict__ sim_conn,    // [H][12]
    const float* __restrict__ sim_mem,   // [H][4096]
    const int* __restrict__ val_conn,    // [H][IB][10]
    const float* __restrict__ val_mem,   // [H][IB][1024]
    const float* __restrict__ agg_mem,   // [H][IB][65]
    const int* __restrict__ out_conn,    // [IB][12]
    const float* __restrict__ out_mem,   // [IB][4096]
    float* __restrict__ out)             // [B][S][IB]
{
    __shared__ uint32_t s_sim[SIM_WORDS];      // [h][128]
    __shared__ uint32_t s_val[VAL_WORDS];      // [h][n][32]
    __shared__ uint32_t s_agg[AGG_WORDS];      // [h][n][3]
    __shared__ uint32_t s_tok[NS];             // packed tokens for this b
    __shared__ uint32_t s_ipart[NS][NH];
    __shared__ uint32_t s_jpart[NS][NH];
    __shared__ uint64_t s_att[NS][NH];         // attend mask over j (causal)
    __shared__ uint64_t s_proj[NH][NIB];       // proj mask over j
    __shared__ uint32_t s_comb[NS][NH];        // combined bits: word h, bit n

    const int tid = threadIdx.x;
    const int b = blockIdx.x;

    // ---- Stage 0/1: stage packed tables + tokens into LDS ----
    if (USE_WS) {
        const uint32_t* wtok = ws;
        const uint32_t* wsim = ws + TOK_WORDS;
        const uint32_t* wval = wsim + SIM_WORDS;
        const uint32_t* wagg = wval + VAL_WORDS;
        for (int i = tid; i < SIM_WORDS; i += 256) s_sim[i] = wsim[i];
        for (int i = tid; i < VAL_WORDS; i += 256) s_val[i] = wval[i];
        for (int i = tid; i < AGG_WORDS; i += 256) s_agg[i] = wagg[i];
        if (tid < NS) s_tok[tid] = wtok[b * NS + tid];
    } else {
        for (int i = tid; i < SIM_WORDS; i += 256) s_sim[i] = pack32_f4(sim_mem + i * 32);
        for (int i = tid; i < VAL_WORDS; i += 256) s_val[i] = pack32_f4(val_mem + i * 32);
        for (int i = tid; i < AGG_WORDS; i += 256) {
            int hn = i / 3, w = i % 3;
            uint32_t v = 0;
            for (int c = 0; c < 32; ++c) {
                int cnt = w * 32 + c;
                if (cnt < NS + 1) v |= (uint32_t)(agg_mem[hn * (NS + 1) + cnt] > 0.5f) << c;
            }
            s_agg[i] = v;
        }
        if (tid < NS) {
            const int* p = tokens + (b * NS + tid) * NIB;
            uint32_t v = 0;
#pragma unroll
            for (int c = 0; c < NIB; ++c) v |= (uint32_t)(p[c] & 1) << c;
            s_tok[tid] = v;
        }
    }
    __syncthreads();

    // ---- Stage 2: ipart/jpart of sim address, per (s,h) ----
    {
        int s = tid >> 2, h = tid & 3;
        uint32_t tk = s_tok[s];
        uint32_t ip = 0, jp = 0;
#pragma unroll
        for (int t = 0; t < SIMB; ++t) {
            int c = sim_conn[h * SIMB + t];
            uint32_t w = 1u << (SIMB - 1 - t);
            if (c < 32)      ip += ((tk >> c) & 1u) * w;                       // qb: tokens[i]
            else if (c < 64) jp += ((tk >> (c - 32)) & 1u) * w;                // kb: tokens[j]
            else if (c < 70) ip += (((uint32_t)s >> (69 - c)) & 1u) * w;       // qp: pb[i]
            else             jp += (((uint32_t)s >> (75 - c)) & 1u) * w;       // kp: pb[j]
        }
        s_ipart[s][h] = ip;
        s_jpart[s][h] = jp;
    }
    __syncthreads();

    // ---- Stage 3: proj masks over j, per (h,n) (threads 0..127) ----
    if (tid < NH * NIB) {
        int h = tid >> 5, n = tid & 31;
        int conn[VALB];
#pragma unroll
        for (int t = 0; t < VALB; ++t) conn[t] = val_conn[(h * NIB + n) * VALB + t];
        uint64_t mask = 0;
        for (int j = 0; j < NS; ++j) {
            uint32_t tk = s_tok[j];
            uint32_t addr = 0;
#pragma unroll
            for (int t = 0; t < VALB; ++t) {
                int c = conn[t];
                uint32_t bit = (c < 32) ? ((tk >> c) & 1u)
                                        : (((uint32_t)j >> (37 - c)) & 1u);   // pb[j]
                addr += bit << (VALB - 1 - t);
            }
            uint32_t bit = (s_val[(h * NIB + n) * 32 + (addr >> 5)] >> (addr & 31)) & 1u;
            mask |= (uint64_t)bit << j;
        }
        s_proj[h][n] = mask;
    }

    // ---- Stage 4: attend masks, per (i,h) (all 256 threads) ----
    {
        int i = tid >> 2, h = tid & 3;
        uint32_t ip = s_ipart[i][h];
        uint64_t mask = 0;
        for (int j = 0; j <= i; ++j) {
            uint32_t addr = ip + s_jpart[j][h];
            uint32_t bit = (s_sim[h * 128 + (addr >> 5)] >> (addr & 31)) & 1u;
            mask |= (uint64_t)bit << j;
        }
        s_att[i][h] = mask;
    }
    __syncthreads();

    // ---- Stage 5: counts -> agg bit -> combined word, per (i,h) ----
    {
        int i = tid >> 2, h = tid & 3;
        uint64_t am = s_att[i][h];
        int na = __popcll(am);
        uint32_t word = 0;
        if (na > 0) {
#pragma unroll
            for (int n = 0; n < NIB; ++n) {
                int cnt = __popcll(am & s_proj[h][n]);   // exact integer count in [0,64]
                uint32_t bit = (s_agg[(h * NIB + n) * 3 + (cnt >> 5)] >> (cnt & 31)) & 1u;
                word |= bit << n;
            }
        }
        s_comb[i][h] = word;
    }
    __syncthreads();

    // ---- Stage 6: out address gather + final float lookup ----
    for (int slot = tid; slot < NS * NIB; slot += 256) {
        int i = slot >> 5;
        int n = slot & 31;
        uint32_t cw0 = s_comb[i][0], cw1 = s_comb[i][1],
                 cw2 = s_comb[i][2], cw3 = s_comb[i][3];
        uint32_t addr = 0;
#pragma unroll
        for (int t = 0; t < OUTB; ++t) {
            int c = out_conn[n * OUTB + t];
            uint32_t w = (c < 64) ? ((c < 32) ? cw0 : cw1) : ((c < 96) ? cw2 : cw3);
            addr += ((w >> (c & 31)) & 1u) << (OUTB - 1 - t);
        }
        out[(b * NS + i) * NIB + n] = out_mem[n * 4096 + addr];
    }
}

extern "C" void kernel_launch(void* const* d_in, const int* in_sizes, int n_in,
                              void* d_out, int out_size, void* d_ws, size_t ws_size,
                              hipStream_t stream) {
    const int*   tokens   = (const int*)d_in[0];
    const int*   sim_conn = (const int*)d_in[1];
    const float* sim_mem  = (const float*)d_in[2];
    const int*   val_conn = (const int*)d_in[3];
    const float* val_mem  = (const float*)d_in[4];
    const float* agg_mem  = (const float*)d_in[5];
    const int*   out_conn = (const int*)d_in[6];
    const float* out_mem  = (const float*)d_in[7];
    float* out = (float*)d_out;

    const size_t need = (size_t)(TOK_WORDS + SIM_WORDS + VAL_WORDS + AGG_WORDS) * sizeof(uint32_t);
    if (ws_size >= need) {
        uint32_t* ws = (uint32_t*)d_ws;
        pack_kernel<<<(TOK_WORDS + 255) / 256, 256, 0, stream>>>(tokens, sim_mem, val_mem, agg_mem, ws);
        ram_main<true><<<NB, 256, 0, stream>>>(ws, tokens, sim_conn, sim_mem, val_conn,
                                               val_mem, agg_mem, out_conn, out_mem, out);
    } else {
        ram_main<false><<<NB, 256, 0, stream>>>(nullptr, tokens, sim_conn, sim_mem, val_conn,
                                                val_mem, agg_mem, out_conn, out_mem, out);
    }
}

// Round 2
// 25.708 us; speedup vs baseline: 1.2834x; 1.2834x over previous
//
#include <hip/hip_runtime.h>
#include <stdint.h>

// Problem constants (match reference)
constexpr int NB = 256;      // batch
constexpr int NS = 64;       // sequence
constexpr int NIB = 32;      // bits per token
constexpr int NH = 4;        // heads
constexpr int SIMB = 12;     // sim address bits
constexpr int VALB = 10;     // val address bits
constexpr int OUTB = 12;     // out address bits

// Packed table layout in ws (uint32 words)
constexpr int TOK_WORDS = NB * NS;        // 16384 : tokens[b,s] -> 32 bits
constexpr int SIM_WORDS = NH * 128;       // 512   : sim_mem[h] -> 4096 bits
constexpr int VAL_WORDS = NH * NIB * 32;  // 4096  : val_mem[h,n] -> 1024 bits
constexpr int AGG_WORDS = NH * NIB * 3;   // 384   : agg_mem[h,n] -> 65 bits (in 96)
constexpr int COMB_WORDS = NB * NS * NH;  // 65536 : comb word per (b,i,h)

__device__ __forceinline__ uint32_t pack32_f4(const float* __restrict__ p) {
    uint32_t v = 0;
    const float4* q = reinterpret_cast<const float4*>(p);
#pragma unroll
    for (int k = 0; k < 8; ++k) {
        float4 f = q[k];
        v |= (uint32_t)(f.x > 0.5f) << (4 * k + 0);
        v |= (uint32_t)(f.y > 0.5f) << (4 * k + 1);
        v |= (uint32_t)(f.z > 0.5f) << (4 * k + 2);
        v |= (uint32_t)(f.w > 0.5f) << (4 * k + 3);
    }
    return v;
}

__global__ __launch_bounds__(256) void pack_kernel(
    const int* __restrict__ tokens, const float* __restrict__ sim_mem,
    const float* __restrict__ val_mem, const float* __restrict__ agg_mem,
    uint32_t* __restrict__ ws)
{
    int tid = blockIdx.x * blockDim.x + threadIdx.x;
    uint32_t* wtok = ws;
    uint32_t* wsim = ws + TOK_WORDS;
    uint32_t* wval = wsim + SIM_WORDS;
    uint32_t* wagg = wval + VAL_WORDS;
    if (tid < TOK_WORDS) {
        const int* p = tokens + tid * NIB;
        uint32_t v = 0;
#pragma unroll
        for (int c = 0; c < NIB; ++c) v |= (uint32_t)(p[c] & 1) << c;
        wtok[tid] = v;
    }
    if (tid < SIM_WORDS) wsim[tid] = pack32_f4(sim_mem + tid * 32);
    if (tid < VAL_WORDS) wval[tid] = pack32_f4(val_mem + tid * 32);
    if (tid < AGG_WORDS) {
        int hn = tid / 3, w = tid % 3;
        uint32_t v = 0;
        for (int c = 0; c < 32; ++c) {
            int cnt = w * 32 + c;
            if (cnt < NS + 1) v |= (uint32_t)(agg_mem[hn * (NS + 1) + cnt] > 0.5f) << c;
        }
        wagg[tid] = v;
    }
}

// ---- main logic: one block per (b,h). 256 threads = 4 waves; lane = j. ----
__global__ __launch_bounds__(256) void head_kernel(
    const uint32_t* __restrict__ ws,
    const int* __restrict__ sim_conn,    // [H][12]
    const int* __restrict__ val_conn,    // [H][IB][10]
    uint32_t* __restrict__ wcomb)        // [B][S][H]
{
    const int bh = blockIdx.x;
    const int b = bh >> 2, h = bh & 3;
    const int tid = threadIdx.x;
    const int lane = tid & 63;
    const int wave = tid >> 6;

    __shared__ uint32_t s_tok[NS];
    __shared__ uint32_t s_sim[128];
    __shared__ uint32_t s_val[NIB * 32];
    __shared__ uint32_t s_agg[NIB * 3];
    __shared__ uint32_t s_ip[NS];
    __shared__ uint32_t s_jp[NS];
    __shared__ uint64_t s_att[NS];
    __shared__ uint64_t s_proj[NIB];

    const uint32_t* wtok = ws;
    const uint32_t* wsim = ws + TOK_WORDS;
    const uint32_t* wval = wsim + SIM_WORDS;
    const uint32_t* wagg = wval + VAL_WORDS;

    // stage packed tables for this (b,h)
    if (tid < NS)  s_tok[tid] = wtok[b * NS + tid];
    if (tid < 128) s_sim[tid] = wsim[h * 128 + tid];
    for (int i = tid; i < NIB * 32; i += 256) s_val[i] = wval[h * NIB * 32 + i];
    if (tid < NIB * 3) s_agg[tid] = wagg[h * NIB * 3 + tid];
    __syncthreads();

    // per-lane token word + 38-bit val_in vector: V bit c == val_in[j=lane][c]
    const uint32_t tkj = s_tok[lane];
    const uint32_t rev6 = __brev((uint32_t)lane) >> 26;           // bit m = bit(5-m) of lane
    const uint64_t V = (uint64_t)tkj | ((uint64_t)rev6 << 32);

    // ---- stage 2 (wave 0 only, lane = s): split sim address into i/j parts ----
    if (wave == 0) {
        const int s = lane;
        uint32_t ip = 0, jp = 0;
#pragma unroll
        for (int t = 0; t < SIMB; ++t) {
            int c = sim_conn[h * SIMB + t];
            uint32_t w = 1u << (SIMB - 1 - t);
            if (c < 32)      ip += ((tkj >> c) & 1u) * w;                    // qb
            else if (c < 64) jp += ((tkj >> (c - 32)) & 1u) * w;             // kb
            else if (c < 70) ip += (((uint32_t)s >> (69 - c)) & 1u) * w;     // qp
            else             jp += (((uint32_t)s >> (75 - c)) & 1u) * w;     // kp
        }
        s_ip[s] = ip;
        s_jp[s] = jp;
    }

    // ---- stage 3: proj masks via ballot. wave w handles n in [8w, 8w+8). ----
    {
        const int n0 = wave * 8;
        for (int nn = 0; nn < 8; ++nn) {
            const int n = n0 + nn;
            const int* conn = val_conn + (h * NIB + n) * VALB;
            uint32_t addr = 0;
#pragma unroll
            for (int t = 0; t < VALB; ++t) {
                int c = conn[t];
                addr += (uint32_t)((V >> c) & 1ull) << (VALB - 1 - t);
            }
            uint32_t bit = (s_val[n * 32 + (addr >> 5)] >> (addr & 31)) & 1u;
            uint64_t m = __ballot((int)bit);
            if (lane == 0) s_proj[n] = m;
        }
    }
    __syncthreads();   // covers stage 2 + stage 3 writes

    // ---- stage 4: attend masks via ballot. wave w handles i in [16w, 16w+16). ----
    {
        const uint32_t jp = s_jp[lane];
        const int i0 = wave * 16;
        for (int ii = 0; ii < 16; ++ii) {
            const int i = i0 + ii;
            uint32_t addr = s_ip[i] + jp;
            uint32_t bit = (s_sim[addr >> 5] >> (addr & 31)) & 1u;
            uint64_t m = __ballot((int)bit);
            if (lane == 0) s_att[i] = m & (~0ull >> (63 - i));   // causal
        }
    }
    __syncthreads();

    // ---- stage 5: counts -> agg bit -> comb word. thread = (i, quarter). ----
    {
        const int i = tid >> 2, q = tid & 3;
        const uint64_t am = s_att[i];
        uint32_t word = 0;
        const int n0 = q * 8;
#pragma unroll
        for (int nn = 0; nn < 8; ++nn) {
            const int n = n0 + nn;
            int cnt = __popcll(am & s_proj[n]);
            uint32_t bit = (s_agg[n * 3 + (cnt >> 5)] >> (cnt & 31)) & 1u;
            word |= bit << n;
        }
        word = (am != 0ull) ? word : 0u;      // n_att > 0.5 gate (branchless, quad-uniform)
        word |= __shfl_xor(word, 1);
        word |= __shfl_xor(word, 2);
        if (q == 0) wcomb[(b * NS + i) * NH + h] = word;
    }
}

// ---- stage 6: output gather. block = (b, half of i-range); 256 threads. ----
__global__ __launch_bounds__(256) void out_kernel(
    const uint32_t* __restrict__ wcomb,
    const int* __restrict__ out_conn,    // [IB][12]
    const float* __restrict__ out_mem,   // [IB][4096]
    float* __restrict__ out)             // [B][S][IB]
{
    const int bid = blockIdx.x;
    const int b = bid >> 1, half = bid & 1;
    const int tid = threadIdx.x;

    __shared__ uint32_t s_comb[32 * NH];     // i_local in [0,32) x h
    __shared__ int s_conn[NIB * OUTB];

    if (tid < 128) s_comb[tid] = wcomb[(b * NS + half * 32) * NH + tid];
    for (int i = tid; i < NIB * OUTB; i += 256) s_conn[i] = out_conn[i];
    __syncthreads();

    const int n = tid & 31;
    int conn[OUTB];
#pragma unroll
    for (int t = 0; t < OUTB; ++t) conn[t] = s_conn[n * OUTB + t];
    const float* om = out_mem + n * 4096;
    const int i0 = tid >> 5;
    const int base = (b * NS + half * 32) * NIB;

#pragma unroll
    for (int k = 0; k < 4; ++k) {
        const int il = i0 + 8 * k;
        uint32_t cw0 = s_comb[il * 4 + 0], cw1 = s_comb[il * 4 + 1];
        uint32_t cw2 = s_comb[il * 4 + 2], cw3 = s_comb[il * 4 + 3];
        uint64_t lo = (uint64_t)cw0 | ((uint64_t)cw1 << 32);
        uint64_t hi = (uint64_t)cw2 | ((uint64_t)cw3 << 32);
        uint32_t addr = 0;
#pragma unroll
        for (int t = 0; t < OUTB; ++t) {
            int c = conn[t];
            uint64_t w = (c < 64) ? lo : hi;
            addr += (uint32_t)((w >> (c & 63)) & 1ull) << (OUTB - 1 - t);
        }
        out[base + k * 256 + tid] = om[addr];
    }
}

// ---- fallback: round-1 monolithic kernel (used only if ws is too small) ----
__global__ __launch_bounds__(256) void ram_main_fallback(
    const int* __restrict__ tokens,
    const int* __restrict__ sim_conn, const float* __restrict__ sim_mem,
    const int* __restrict__ val_conn, const float* __restrict__ val_mem,
    const float* __restrict__ agg_mem,
    const int* __restrict__ out_conn, const float* __restrict__ out_mem,
    float* __restrict__ out)
{
    __shared__ uint32_t s_sim[SIM_WORDS];
    __shared__ uint32_t s_val[VAL_WORDS];
    __shared__ uint32_t s_agg[AGG_WORDS];
    __shared__ uint32_t s_tok[NS];
    __shared__ uint32_t s_ipart[NS][NH];
    __shared__ uint32_t s_jpart[NS][NH];
    __shared__ uint64_t s_att[NS][NH];
    __shared__ uint64_t s_proj[NH][NIB];
    __shared__ uint32_t s_comb[NS][NH];

    const int tid = threadIdx.x;
    const int b = blockIdx.x;

    for (int i = tid; i < SIM_WORDS; i += 256) s_sim[i] = pack32_f4(sim_mem + i * 32);
    for (int i = tid; i < VAL_WORDS; i += 256) s_val[i] = pack32_f4(val_mem + i * 32);
    for (int i = tid; i < AGG_WORDS; i += 256) {
        int hn = i / 3, w = i % 3;
        uint32_t v = 0;
        for (int c = 0; c < 32; ++c) {
            int cnt = w * 32 + c;
            if (cnt < NS + 1) v |= (uint32_t)(agg_mem[hn * (NS + 1) + cnt] > 0.5f) << c;
        }
        s_agg[i] = v;
    }
    if (tid < NS) {
        const int* p = tokens + (b * NS + tid) * NIB;
        uint32_t v = 0;
#pragma unroll
        for (int c = 0; c < NIB; ++c) v |= (uint32_t)(p[c] & 1) << c;
        s_tok[tid] = v;
    }
    __syncthreads();

    {
        int s = tid >> 2, h = tid & 3;
        uint32_t tk = s_tok[s];
        uint32_t ip = 0, jp = 0;
#pragma unroll
        for (int t = 0; t < SIMB; ++t) {
            int c = sim_conn[h * SIMB + t];
            uint32_t w = 1u << (SIMB - 1 - t);
            if (c < 32)      ip += ((tk >> c) & 1u) * w;
            else if (c < 64) jp += ((tk >> (c - 32)) & 1u) * w;
            else if (c < 70) ip += (((uint32_t)s >> (69 - c)) & 1u) * w;
            else             jp += (((uint32_t)s >> (75 - c)) & 1u) * w;
        }
        s_ipart[s][h] = ip;
        s_jpart[s][h] = jp;
    }
    __syncthreads();

    if (tid < NH * NIB) {
        int h = tid >> 5, n = tid & 31;
        int conn[VALB];
#pragma unroll
        for (int t = 0; t < VALB; ++t) conn[t] = val_conn[(h * NIB + n) * VALB + t];
        uint64_t mask = 0;
        for (int j = 0; j < NS; ++j) {
            uint32_t tk = s_tok[j];
            uint32_t addr = 0;
#pragma unroll
            for (int t = 0; t < VALB; ++t) {
                int c = conn[t];
                uint32_t bit = (c < 32) ? ((tk >> c) & 1u)
                                        : (((uint32_t)j >> (37 - c)) & 1u);
                addr += bit << (VALB - 1 - t);
            }
            uint32_t bit = (s_val[(h * NIB + n) * 32 + (addr >> 5)] >> (addr & 31)) & 1u;
            mask |= (uint64_t)bit << j;
        }
        s_proj[h][n] = mask;
    }

    {
        int i = tid >> 2, h = tid & 3;
        uint32_t ip = s_ipart[i][h];
        uint64_t mask = 0;
        for (int j = 0; j <= i; ++j) {
            uint32_t addr = ip + s_jpart[j][h];
            uint32_t bit = (s_sim[h * 128 + (addr >> 5)] >> (addr & 31)) & 1u;
            mask |= (uint64_t)bit << j;
        }
        s_att[i][h] = mask;
    }
    __syncthreads();

    {
        int i = tid >> 2, h = tid & 3;
        uint64_t am = s_att[i][h];
        uint32_t word = 0;
        if (am) {
#pragma unroll
            for (int n = 0; n < NIB; ++n) {
                int cnt = __popcll(am & s_proj[h][n]);
                uint32_t bit = (s_agg[(h * NIB + n) * 3 + (cnt >> 5)] >> (cnt & 31)) & 1u;
                word |= bit << n;
            }
        }
        s_comb[i][h] = word;
    }
    __syncthreads();

    for (int slot = tid; slot < NS * NIB; slot += 256) {
        int i = slot >> 5;
        int n = slot & 31;
        uint32_t cw0 = s_comb[i][0], cw1 = s_comb[i][1],
                 cw2 = s_comb[i][2], cw3 = s_comb[i][3];
        uint32_t addr = 0;
#pragma unroll
        for (int t = 0; t < OUTB; ++t) {
            int c = out_conn[n * OUTB + t];
            uint32_t w = (c < 64) ? ((c < 32) ? cw0 : cw1) : ((c < 96) ? cw2 : cw3);
            addr += ((w >> (c & 31)) & 1u) << (OUTB - 1 - t);
        }
        out[(b * NS + i) * NIB + n] = out_mem[n * 4096 + addr];
    }
}

extern "C" void kernel_launch(void* const* d_in, const int* in_sizes, int n_in,
                              void* d_out, int out_size, void* d_ws, size_t ws_size,
                              hipStream_t stream) {
    const int*   tokens   = (const int*)d_in[0];
    const int*   sim_conn = (const int*)d_in[1];
    const float* sim_mem  = (const float*)d_in[2];
    const int*   val_conn = (const int*)d_in[3];
    const float* val_mem  = (const float*)d_in[4];
    const float* agg_mem  = (const float*)d_in[5];
    const int*   out_conn = (const int*)d_in[6];
    const float* out_mem  = (const float*)d_in[7];
    float* out = (float*)d_out;

    const size_t need =
        (size_t)(TOK_WORDS + SIM_WORDS + VAL_WORDS + AGG_WORDS + COMB_WORDS) * sizeof(uint32_t);
    if (ws_size >= need) {
        uint32_t* ws = (uint32_t*)d_ws;
        uint32_t* wcomb = ws + TOK_WORDS + SIM_WORDS + VAL_WORDS + AGG_WORDS;
        pack_kernel<<<(TOK_WORDS + 255) / 256, 256, 0, stream>>>(tokens, sim_mem, val_mem, agg_mem, ws);
        head_kernel<<<NB * NH, 256, 0, stream>>>(ws, sim_conn, val_conn, wcomb);
        out_kernel<<<NB * 2, 256, 0, stream>>>(wcomb, out_conn, out_mem, out);
    } else {
        ram_main_fallback<<<NB, 256, 0, stream>>>(tokens, sim_conn, sim_mem, val_conn,
                                                  val_mem, agg_mem, out_conn, out_mem, out);
    }
}